// Round 1
// baseline (457.503 us; speedup 1.0000x reference)
//
#include <hip/hip_runtime.h>
#include <hip/hip_bf16.h>
#include <math.h>

// Problem constants
#define BB   64
#define TT   32
#define CC   256
#define SS   289
#define KK   16384
#define G1c  4.0f
#define G2c  5.0f
#define G3c  10.0f
#define INV_T 20.0f
#define EPSF 1e-8f

// Workspace layout (floats)
#define WS_SIM 0
#define WS_S0  4096
#define WS_S2  8192
#define WS_CN  12288
#define WS_RN  28672
#define WS_CAN 45056
#define WS_RAN 61440
#define WS_QN  77824
#define WS_PM  79872   // [2][64][16]
#define WS_PS  81920   // [2][64][16]
#define WS_F32_TOTAL 83968

#define CTXT_ELEMS (64*304*256)
#define CTXC_ELEMS (64*256*320)
#define WQ_ELEMS   (64*32*256)

typedef __attribute__((ext_vector_type(8))) short short8;
typedef __attribute__((ext_vector_type(4))) float float4v;

__device__ __forceinline__ float4v mfma_bf16(short8 a, short8 b, float4v c) {
    return __builtin_amdgcn_mfma_f32_16x16x32_bf16(a, b, c, 0, 0, 0);
}

__device__ __forceinline__ short f2bf(float f) {
    union { float f; unsigned u; } x; x.f = f;
    unsigned r = x.u + 0x7FFFu + ((x.u >> 16) & 1u);
    return (short)(r >> 16);
}

// ---------------------------------------------------------------------------
// Prep: normalize codes, word norms, bf16 conversions of ctx (2 layouts) + q
// grid: [0,256) codes | [256,2304) qn | [2304,3520) ctxT | [3520,3904) ctxC |
//       [3904,3968) wq
// ---------------------------------------------------------------------------
__global__ __launch_bounds__(256) void prep_kernel(
    const float* __restrict__ cnn, const float* __restrict__ rnn,
    const float* __restrict__ img, const float* __restrict__ wemb,
    const float* __restrict__ cnnA, const float* __restrict__ rnnA,
    float* __restrict__ W)
{
    int bid = blockIdx.x, tid = threadIdx.x;
    short* B16 = (short*)(W + WS_F32_TOTAL);
    short* ctxT = B16;
    short* ctxC = B16 + CTXT_ELEMS;
    short* wq   = B16 + CTXT_ELEMS + CTXC_ELEMS;

    if (bid < 256) {
        int mat = bid >> 6, row = bid & 63;
        const float* src = (mat==0)? cnn : (mat==1)? rnn : (mat==2)? cnnA : rnnA;
        float* dst = W + ((mat==0)? WS_CN : (mat==1)? WS_RN : (mat==2)? WS_CAN : WS_RAN);
        float v = src[row*256 + tid];
        float ss = v*v;
        for (int o=1;o<64;o<<=1) ss += __shfl_xor(ss,o);
        __shared__ float sc[4];
        if ((tid&63)==0) sc[tid>>6] = ss;
        __syncthreads();
        float tot = sc[0]+sc[1]+sc[2]+sc[3];
        float inv = 1.0f / fmaxf(sqrtf(tot), EPSF);
        dst[row*256+tid] = v*inv;
    } else if (bid < 2304) {
        int b2 = bid - 256; int i = b2 >> 5, t = b2 & 31;
        float v = wemb[(i*32 + t)*256 + tid];
        float ss = v*v;
        for (int o=1;o<64;o<<=1) ss += __shfl_xor(ss,o);
        __shared__ float sc2[4];
        if ((tid&63)==0) sc2[tid>>6] = ss;
        __syncthreads();
        if (tid==0) W[WS_QN + i*32 + t] = sqrtf(sc2[0]+sc2[1]+sc2[2]+sc2[3]);
    } else if (bid < 3520) {
        // ctxT[j][s][c] bf16, s padded to 304 (zeros for s>=289)
        int b3 = bid - 2304; int j = b3 / 19, mt = b3 % 19, s0 = mt*16;
        __shared__ float tile[16*257];
        for (int idx = tid; idx < 4096; idx += 256) {
            int c = idx >> 4, sl = idx & 15, s = s0 + sl;
            float v = (s < 289) ? img[((size_t)(j*256 + c))*289 + s] : 0.0f;
            tile[sl*257 + c] = v;
        }
        __syncthreads();
        for (int idx = tid; idx < 4096; idx += 256) {
            int orr = idx >> 8, c = idx & 255;
            ctxT[((size_t)(j*304 + s0 + orr))*256 + c] = f2bf(tile[orr*257 + c]);
        }
    } else if (bid < 3904) {
        // ctxC[j][c][s] bf16, s padded to 320
        for (size_t idx = (size_t)(bid-3520)*256 + tid; idx < (size_t)CTXC_ELEMS; idx += (size_t)384*256) {
            int s = (int)(idx % 320); size_t rem = idx / 320;
            int c = (int)(rem & 255); int j = (int)(rem >> 8);
            float v = (s < 289) ? img[((size_t)(j*256 + c))*289 + s] : 0.0f;
            ctxC[idx] = f2bf(v);
        }
    } else {
        for (int idx = (bid-3904)*256 + tid; idx < WQ_ELEMS; idx += 64*256) {
            wq[idx] = f2bf(wemb[idx]);
        }
    }
}

// ---------------------------------------------------------------------------
// MoCo logits: online logsumexp partials over queue chunks.
// grid 256: mu(2) x rowgroup(8 rows x 8) x chunk(16 x 1024 cols)
// ---------------------------------------------------------------------------
__global__ __launch_bounds__(256) void moco_kernel(
    const float* __restrict__ queue, const float* __restrict__ queueIm,
    float* __restrict__ W)
{
    int bid = blockIdx.x, tid = threadIdx.x;
    int mu = bid >> 7;
    int rg = (bid >> 4) & 7;
    int ch = bid & 15;
    const float* Q = mu ? queueIm : queue;
    const float* code = W + (mu ? WS_RN : WS_CN);
    __shared__ float code_l[8*256];
    int r0 = rg*8;
    for (int idx = tid; idx < 2048; idx += 256)
        code_l[idx] = code[r0*256 + idx];
    __syncthreads();

    int kbase = ch*1024 + tid;
    float dots[8][4];
    for (int r=0;r<8;r++) for(int p=0;p<4;p++) dots[r][p]=0.f;
    for (int c = 0; c < 256; c++) {
        float qv0 = Q[(size_t)c*KK + kbase];
        float qv1 = Q[(size_t)c*KK + kbase + 256];
        float qv2 = Q[(size_t)c*KK + kbase + 512];
        float qv3 = Q[(size_t)c*KK + kbase + 768];
        for (int r=0;r<8;r++) {
            float cv = code_l[r*256 + c];
            dots[r][0] += cv*qv0; dots[r][1] += cv*qv1;
            dots[r][2] += cv*qv2; dots[r][3] += cv*qv3;
        }
    }
    float m[8], s[8];
    for (int r=0;r<8;r++){ m[r] = -1e30f; s[r] = 0.f; }
    for (int p=0;p<4;p++) for (int r=0;r<8;r++) {
        float v = dots[r][p]*INV_T;
        float nm = fmaxf(m[r], v);
        s[r] = s[r]*__expf(m[r]-nm) + __expf(v-nm);
        m[r] = nm;
    }
    __shared__ float wm[4][8], ws2[4][8];
    int lane = tid&63, wave = tid>>6;
    for (int r=0;r<8;r++) {
        float mm = m[r], ss = s[r];
        for (int o=1;o<64;o<<=1) {
            float om = __shfl_xor(mm,o), os = __shfl_xor(ss,o);
            float nm = fmaxf(mm,om);
            ss = ss*__expf(mm-nm) + os*__expf(om-nm);
            mm = nm;
        }
        if (lane==0){ wm[wave][r]=mm; ws2[wave][r]=ss; }
    }
    __syncthreads();
    if (tid < 8) {
        float mm = wm[0][tid], ss = ws2[0][tid];
        for (int w=1;w<4;w++) {
            float om = wm[w][tid], os = ws2[w][tid];
            float nm = fmaxf(mm,om);
            ss = ss*__expf(mm-nm) + os*__expf(om-nm);
            mm = nm;
        }
        int row = r0 + tid;
        W[WS_PM + (mu*64 + row)*16 + ch] = mm;
        W[WS_PS + (mu*64 + row)*16 + ch] = ss;
    }
}

// ---------------------------------------------------------------------------
// Attention: per (i,j) block -> sim_raw[i][j] = logsumexp_t(G2*cos[t])
// ---------------------------------------------------------------------------
__global__ __launch_bounds__(256, 2) void attn_kernel(float* __restrict__ W)
{
    __shared__ float scores[304*33];          // 40128 B
    __shared__ short attnT[32*328];           // 20992 B, [t][s] s-contig
    __shared__ float rowm[304], rowinv[304];
    __shared__ float mpart[4][32], dpart[4][32], numpart[4][32];
    __shared__ float wn2l[32];

    const short* B16 = (const short*)(W + WS_F32_TOTAL);
    const short* ctxT = B16;
    const short* ctxC = B16 + CTXT_ELEMS;
    const short* wq   = B16 + CTXT_ELEMS + CTXC_ELEMS;

    int bid = blockIdx.x;
    int j = bid >> 6, i = bid & 63;
    int tid = threadIdx.x, lane = tid & 63, wave = tid >> 6;
    int lo16 = lane & 15, quad = lane >> 4;

    // zero K-padding of attnT (s in [289,320)) so phase C pads are clean
    for (int idx = tid; idx < 992; idx += 256) {
        int t = idx / 31, s = 289 + idx % 31;
        attnT[t*328 + s] = 0;
    }
    if (tid < 32) wn2l[tid] = 0.f;

    // ---- phase A: scores[s][t] = sum_c ctxT[j][s][c] * wq[i][t][c] (MFMA)
    {
        const short* ctxTj = ctxT + (size_t)j * (304*256);
        const short* wqi   = wq + i * (32*256);
        const short* bRow0 = wqi + lo16*256 + quad*8;
        const short* bRow1 = wqi + (16+lo16)*256 + quad*8;
        for (int mt = wave; mt < 19; mt += 4) {
            int s0 = mt*16;
            const short* aRow = ctxTj + (s0 + lo16)*256 + quad*8;
            float4v acc0 = {0.f,0.f,0.f,0.f}, acc1 = {0.f,0.f,0.f,0.f};
            for (int kk = 0; kk < 8; kk++) {
                short8 a  = *(const short8*)(aRow + kk*32);
                short8 b0 = *(const short8*)(bRow0 + kk*32);
                short8 b1 = *(const short8*)(bRow1 + kk*32);
                acc0 = mfma_bf16(a, b0, acc0);
                acc1 = mfma_bf16(a, b1, acc1);
            }
            int srow = s0 + quad*4;
            for (int r = 0; r < 4; r++) {
                scores[(srow+r)*33 + lo16]      = acc0[r];
                scores[(srow+r)*33 + 16 + lo16] = acc1[r];
            }
        }
    }
    __syncthreads();

    // ---- B1: per-s softmax stats over t
    for (int s = tid; s < 289; s += 256) {
        float mx = -1e30f;
        for (int t = 0; t < 32; t++) mx = fmaxf(mx, scores[s*33+t]);
        float z = 0.f;
        for (int t = 0; t < 32; t++) z += __expf(scores[s*33+t]-mx);
        rowm[s] = mx; rowinv[s] = 1.0f/z;
    }
    __syncthreads();

    // ---- B2: softmax over s of G1*attn1, write attnT (bf16), num[t]
    int tt = tid & 31, sub = tid >> 5;
    float mB = -1e30f, dB = 0.f;
    for (int s = sub; s < 289; s += 8) {
        float a1 = __expf(scores[s*33+tt]-rowm[s])*rowinv[s];
        float v = G1c*a1;
        float nm = fmaxf(mB, v);
        dB = dB*__expf(mB-nm) + __expf(v-nm);
        mB = nm;
    }
    {
        float om = __shfl_xor(mB, 32), od = __shfl_xor(dB, 32);
        float nm = fmaxf(mB, om);
        dB = dB*__expf(mB-nm) + od*__expf(om-nm);
        mB = nm;
    }
    if (lane < 32) { mpart[wave][tt] = mB; dpart[wave][tt] = dB; }
    __syncthreads();
    float Mt = -1e30f, Dt = 0.f;
    for (int w = 0; w < 4; w++) {
        float om = mpart[w][tt], od = dpart[w][tt];
        float nm = fmaxf(Mt, om);
        Dt = Dt*__expf(Mt-nm) + od*__expf(om-nm);
        Mt = nm;
    }
    float invD = 1.0f/Dt;
    float numacc = 0.f;
    for (int s = sub; s < 289; s += 8) {
        float sc = scores[s*33+tt];
        float a1 = __expf(sc-rowm[s])*rowinv[s];
        float av = __expf(G1c*a1 - Mt)*invD;
        attnT[tt*328 + s] = f2bf(av);
        numacc += av*sc;
    }
    numacc += __shfl_xor(numacc, 32);
    if (lane < 32) numpart[wave][tt] = numacc;
    __syncthreads();

    // ---- phase C: wC = ctxC[j] (256xS) x attn (SxT) via MFMA; keep only wn2
    {
        const short* ctxCj = ctxC + (size_t)j * (256*320);
        float4v zero = {0.f,0.f,0.f,0.f};
        float4v acc[4][2];
        for (int m2=0; m2<4; m2++){ acc[m2][0] = zero; acc[m2][1] = zero; }
        for (int kk = 0; kk < 10; kk++) {
            short8 b0 = *(const short8*)(&attnT[lo16*328 + kk*32 + quad*8]);
            short8 b1 = *(const short8*)(&attnT[(16+lo16)*328 + kk*32 + quad*8]);
            for (int m2 = 0; m2 < 4; m2++) {
                int c0 = (wave*4 + m2)*16;
                short8 a = *(const short8*)(ctxCj + (c0+lo16)*320 + kk*32 + quad*8);
                acc[m2][0] = mfma_bf16(a, b0, acc[m2][0]);
                acc[m2][1] = mfma_bf16(a, b1, acc[m2][1]);
            }
        }
        for (int nt = 0; nt < 2; nt++) {
            float ss = 0.f;
            for (int m2=0;m2<4;m2++)
                for (int r=0;r<4;r++){ float v = acc[m2][nt][r]; ss += v*v; }
            ss += __shfl_xor(ss, 16);
            ss += __shfl_xor(ss, 32);
            if (lane < 16) atomicAdd(&wn2l[nt*16 + lane], ss);
        }
    }
    __syncthreads();

    // ---- epilogue: cos, logsumexp over t -> sim
    if (wave == 0) {
        float v;
        if (lane < 32) {
            float num = numpart[0][lane]+numpart[1][lane]+numpart[2][lane]+numpart[3][lane];
            float wn = sqrtf(wn2l[lane]);
            float qv = W[WS_QN + i*32 + lane];
            float den = fmaxf(qv*wn, EPSF);
            v = G2c * (num/den);
        } else v = -1e30f;
        float mx = v;
        for (int o=1;o<64;o<<=1) mx = fmaxf(mx, __shfl_xor(mx,o));
        float e = (lane<32)? __expf(v-mx) : 0.f;
        for (int o=1;o<64;o<<=1) e += __shfl_xor(e,o);
        if (lane==0) W[WS_SIM + i*64 + j] = mx + __logf(e);
    }
}

// ---------------------------------------------------------------------------
// s0 = G3*cn@rn^T, s2 = G3*rn@ran^T   (grid 64, one i per block)
// ---------------------------------------------------------------------------
__global__ __launch_bounds__(256) void smat_kernel(float* __restrict__ W)
{
    int i = blockIdx.x, tid = threadIdx.x, lane = tid&63, wave = tid>>6;
    __shared__ float a0[256], a1[256];
    __shared__ float part[2][64][4];
    a0[tid] = W[WS_CN + i*256 + tid];
    a1[tid] = W[WS_RN + i*256 + tid];
    __syncthreads();
    const float* B0 = W + WS_RN;
    const float* B1 = W + WS_RAN;
    float av0 = a0[tid], av1 = a1[tid];
    for (int jj = 0; jj < 64; jj++) {
        float v0 = av0 * B0[jj*256 + tid];
        float v1 = av1 * B1[jj*256 + tid];
        for (int o=1;o<64;o<<=1){ v0 += __shfl_xor(v0,o); v1 += __shfl_xor(v1,o); }
        if (lane==0){ part[0][jj][wave]=v0; part[1][jj][wave]=v1; }
    }
    __syncthreads();
    if (tid < 128) {
        int mat = tid>>6, jj = tid&63;
        float s = part[mat][jj][0]+part[mat][jj][1]+part[mat][jj][2]+part[mat][jj][3];
        W[(mat? WS_S2 : WS_S0) + i*64 + jj] = G3c * s;
    }
}

// ---------------------------------------------------------------------------
// Final: all cross-entropies -> d_out[7]
// ---------------------------------------------------------------------------
__global__ __launch_bounds__(256) void final_kernel(
    const int* __restrict__ labels, float* __restrict__ W, float* __restrict__ out)
{
    int tid = threadIdx.x;
    __shared__ float cearr[6][64];
    __shared__ float cemoco[128];

    if (tid < 128) {
        int mu = tid>>6, r = tid&63;
        float mm = -1e30f, ss = 0.f;
        for (int ch=0; ch<16; ch++) {
            float om = W[WS_PM + (mu*64+r)*16 + ch];
            float os = W[WS_PS + (mu*64+r)*16 + ch];
            float nm = fmaxf(mm, om);
            ss = ss*__expf(mm-nm) + os*__expf(om-nm);
            mm = nm;
        }
        const float* A  = W + (mu? WS_RN : WS_CN) + r*256;
        const float* Bv = W + (mu? WS_CAN : WS_RAN) + r*256;
        float dot = 0.f;
        for (int c=0;c<256;c++) dot += A[c]*Bv[c];
        float v0 = dot*INV_T;
        float nm = fmaxf(mm, v0);
        float S = ss*__expf(mm-nm) + __expf(v0-nm);
        cemoco[tid] = nm + __logf(S) - v0;
    }

    for (int pass=0; pass<2; pass++) {
        int cfg = pass*4 + (tid>>6);
        int row = tid&63;
        if (cfg < 6) {
            const float* mat; float scale; int colMajor;
            if (cfg==0){ mat=W+WS_SIM; scale=G3c; colMajor=1; }
            else if (cfg==1){ mat=W+WS_SIM; scale=G3c; colMajor=0; }
            else if (cfg==2){ mat=W+WS_S0; scale=1.f; colMajor=0; }
            else if (cfg==3){ mat=W+WS_S0; scale=1.f; colMajor=1; }
            else if (cfg==4){ mat=W+WS_S2; scale=1.f; colMajor=0; }
            else            { mat=W+WS_S2; scale=1.f; colMajor=1; }
            float mx = -1e30f;
            for (int x=0;x<64;x++) {
                float v = (colMajor? mat[x*64+row] : mat[row*64+x])*scale;
                mx = fmaxf(mx, v);
            }
            float se = 0.f;
            for (int x=0;x<64;x++) {
                float v = (colMajor? mat[x*64+row] : mat[row*64+x])*scale;
                se += __expf(v-mx);
            }
            int lbl = labels[row];
            float diag = (colMajor? mat[lbl*64+row] : mat[row*64+lbl])*scale;
            cearr[cfg][row] = mx + __logf(se) - diag;
        }
    }
    __syncthreads();

    if (tid < 7) {
        float r;
        if (tid == 4) {
            float s0=0.f, s1=0.f;
            for (int k=0;k<64;k++){ s0 += cemoco[k]; s1 += cemoco[64+k]; }
            r = (s0/64.f + s1/64.f)*0.5f;
        } else {
            int cfg = (tid < 4) ? tid : tid - 1;
            float s = 0.f;
            for (int k=0;k<64;k++) s += cearr[cfg][k];
            r = s/64.f;
        }
        out[tid] = r;
    }
}

// ---------------------------------------------------------------------------
extern "C" void kernel_launch(void* const* d_in, const int* in_sizes, int n_in,
                              void* d_out, int out_size, void* d_ws, size_t ws_size,
                              hipStream_t stream)
{
    const float* cnn   = (const float*)d_in[0];
    const float* rnn   = (const float*)d_in[1];
    const float* img   = (const float*)d_in[2];
    const float* wemb  = (const float*)d_in[3];
    const float* cnnA  = (const float*)d_in[4];
    const float* rnnA  = (const float*)d_in[5];
    const float* queue   = (const float*)d_in[6];
    const float* queueIm = (const float*)d_in[7];
    const int*   labels  = (const int*)d_in[9];
    float* W   = (float*)d_ws;
    float* out = (float*)d_out;

    prep_kernel<<<3968, 256, 0, stream>>>(cnn, rnn, img, wemb, cnnA, rnnA, W);
    moco_kernel<<<256, 256, 0, stream>>>(queue, queueIm, W);
    attn_kernel<<<4096, 256, 0, stream>>>(W);
    smat_kernel<<<64, 256, 0, stream>>>(W);
    final_kernel<<<1, 256, 0, stream>>>(labels, W, out);
}

// Round 2
// 387.205 us; speedup vs baseline: 1.1816x; 1.1816x over previous
//
#include <hip/hip_runtime.h>
#include <hip/hip_bf16.h>
#include <math.h>

// Problem constants
#define BB   64
#define TT   32
#define CC   256
#define KK   16384
#define G1c  4.0f
#define G2c  5.0f
#define G3c  10.0f
#define INV_T 20.0f
#define EPSF 1e-8f

// Workspace layout (floats)
#define WS_SIM 0
#define WS_S0  4096
#define WS_S2  8192
#define WS_CN  12288
#define WS_RN  28672
#define WS_CAN 45056
#define WS_RAN 61440
#define WS_QN  77824
#define WS_PM  79872               // [2][64][64]
#define WS_PS  (79872 + 8192)      // [2][64][64]
#define WS_F32_TOTAL (79872 + 16384)

#define CTXT_ELEMS (64*320*256)    // ctxT[j][s(320 pad)][c] bf16
#define WQ_ELEMS   (64*32*256)     // wq[i][t][c] bf16

typedef __attribute__((ext_vector_type(8))) short short8;
typedef __attribute__((ext_vector_type(4))) float float4v;

__device__ __forceinline__ float4v mfma_bf16(short8 a, short8 b, float4v c) {
    return __builtin_amdgcn_mfma_f32_16x16x32_bf16(a, b, c, 0, 0, 0);
}

__device__ __forceinline__ short f2bf(float f) {
    union { float f; unsigned u; } x; x.f = f;
    unsigned r = x.u + 0x7FFFu + ((x.u >> 16) & 1u);
    return (short)(r >> 16);
}

// ---------------------------------------------------------------------------
// Prep: normalize codes, word norms, bf16 ctxT (s padded to 320) + wq
// grid: [0,256) codes | [256,2304) qn | [2304,3584) ctxT | [3584,3648) wq
// ---------------------------------------------------------------------------
__global__ __launch_bounds__(256) void prep_kernel(
    const float* __restrict__ cnn, const float* __restrict__ rnn,
    const float* __restrict__ img, const float* __restrict__ wemb,
    const float* __restrict__ cnnA, const float* __restrict__ rnnA,
    float* __restrict__ W)
{
    int bid = blockIdx.x, tid = threadIdx.x;
    short* B16 = (short*)(W + WS_F32_TOTAL);
    short* ctxT = B16;
    short* wq   = B16 + CTXT_ELEMS;

    if (bid < 256) {
        int mat = bid >> 6, row = bid & 63;
        const float* src = (mat==0)? cnn : (mat==1)? rnn : (mat==2)? cnnA : rnnA;
        float* dst = W + ((mat==0)? WS_CN : (mat==1)? WS_RN : (mat==2)? WS_CAN : WS_RAN);
        float v = src[row*256 + tid];
        float ss = v*v;
        for (int o=1;o<64;o<<=1) ss += __shfl_xor(ss,o);
        __shared__ float sc[4];
        if ((tid&63)==0) sc[tid>>6] = ss;
        __syncthreads();
        float tot = sc[0]+sc[1]+sc[2]+sc[3];
        float inv = 1.0f / fmaxf(sqrtf(tot), EPSF);
        dst[row*256+tid] = v*inv;
    } else if (bid < 2304) {
        int b2 = bid - 256; int i = b2 >> 5, t = b2 & 31;
        float v = wemb[(i*32 + t)*256 + tid];
        float ss = v*v;
        for (int o=1;o<64;o<<=1) ss += __shfl_xor(ss,o);
        __shared__ float sc2[4];
        if ((tid&63)==0) sc2[tid>>6] = ss;
        __syncthreads();
        if (tid==0) W[WS_QN + i*32 + t] = sqrtf(sc2[0]+sc2[1]+sc2[2]+sc2[3]);
    } else if (bid < 3584) {
        // ctxT[j][s][c] bf16, s padded to 320 (zeros for s>=289)
        int b3 = bid - 2304; int j = b3 / 20, mt = b3 % 20, s0 = mt*16;
        __shared__ float tile[16*257];
        for (int idx = tid; idx < 4096; idx += 256) {
            int c = idx >> 4, sl = idx & 15, s = s0 + sl;
            float v = (s < 289) ? img[((size_t)(j*256 + c))*289 + s] : 0.0f;
            tile[sl*257 + c] = v;
        }
        __syncthreads();
        for (int idx = tid; idx < 4096; idx += 256) {
            int orr = idx >> 8, c = idx & 255;
            ctxT[((size_t)(j*320 + s0 + orr))*256 + c] = f2bf(tile[orr*257 + c]);
        }
    } else {
        for (int idx = (bid-3584)*256 + tid; idx < WQ_ELEMS; idx += 64*256) {
            wq[idx] = f2bf(wemb[idx]);
        }
    }
}

// ---------------------------------------------------------------------------
// MoCo: grid 256 = mu(2) x rg(2: 32 rows) x ch(64: 256 cols).
// code rows read via uniform address -> scalar loads; queue read 2x total.
// ---------------------------------------------------------------------------
__global__ __launch_bounds__(256) void moco_kernel(
    const float* __restrict__ queue, const float* __restrict__ queueIm,
    float* __restrict__ W)
{
    int bid = blockIdx.x, tid = threadIdx.x;
    int mu = bid >> 7, rg = (bid >> 6) & 1, ch = bid & 63;
    const float* Q = mu ? queueIm : queue;
    const float* code = W + (mu ? WS_RN : WS_CN) + rg*32*256;
    int col = ch*256 + tid;

    float dots[32];
    #pragma unroll
    for (int r=0;r<32;r++) dots[r] = 0.f;

    for (int c4 = 0; c4 < 64; c4++) {
        float q0 = Q[(size_t)(c4*4+0)*KK + col];
        float q1 = Q[(size_t)(c4*4+1)*KK + col];
        float q2 = Q[(size_t)(c4*4+2)*KK + col];
        float q3 = Q[(size_t)(c4*4+3)*KK + col];
        #pragma unroll
        for (int r=0;r<32;r++) {
            const float4 cv = *(const float4*)&code[r*256 + c4*4];
            dots[r] += cv.x*q0 + cv.y*q1 + cv.z*q2 + cv.w*q3;
        }
    }

    __shared__ float redm[4][32], reds[4][32];
    int lane = tid&63, wave = tid>>6;
    for (int r=0;r<32;r++) {
        float m = dots[r]*INV_T, s = 1.0f;
        for (int o=1;o<64;o<<=1) {
            float om = __shfl_xor(m,o), os = __shfl_xor(s,o);
            float nm = fmaxf(m,om);
            s = s*__expf(m-nm) + os*__expf(om-nm);
            m = nm;
        }
        if (lane==0){ redm[wave][r]=m; reds[wave][r]=s; }
    }
    __syncthreads();
    if (tid < 32) {
        float m = redm[0][tid], s = reds[0][tid];
        for (int w=1;w<4;w++) {
            float om = redm[w][tid], os = reds[w][tid];
            float nm = fmaxf(m,om);
            s = s*__expf(m-nm) + os*__expf(om-nm);
            m = nm;
        }
        int row = rg*32 + tid;
        W[WS_PM + (mu*64 + row)*64 + ch] = m;
        W[WS_PS + (mu*64 + row)*64 + ch] = s;
    }
}

// ---------------------------------------------------------------------------
// Attention: block = (j, i-pair). Stream s in 32-tiles:
//   stage ctx tile -> LDS, transpose in LDS, MFMA scores, softmax-t + e
//   (exponent G1*a1 bounded by 4 -> no running max), wC accumulated in regs.
// cos = num_u / (qn * sqrt(wn2_u))  (the 1/D scaling cancels).
// ---------------------------------------------------------------------------
__global__ __launch_bounds__(256, 3) void attn_kernel(float* __restrict__ W)
{
    __shared__ short ctx_sc[32*264];       // [s][c] pad 264   (16896 B)
    __shared__ short ctx_cs[256*40];       // [c][s] pad 40    (20480 B)
    __shared__ float scoresL[2*32*36];     // [i][s][t] pad 36 (9216 B)
    __shared__ short eT[2*32*40];          // [i][t][s] pad 40 (5120 B)
    __shared__ float Dp[4][32], Np[4][32], wn2L[2][32];

    const short* B16 = (const short*)(W + WS_F32_TOTAL);
    const short* ctxT = B16;
    const short* wq   = B16 + CTXT_ELEMS;

    int bid = blockIdx.x;
    int j = bid >> 5, ip = bid & 31;
    int tid = threadIdx.x, lane = tid & 63, wave = tid >> 6;
    int lo16 = lane & 15, quad = lane >> 4;
    int i_l = wave >> 1, nt = wave & 1;       // wave -> (i_local, t-half)
    int i_g = ip*2 + i_l;

    // wq fragments for this wave's (i, t-half), kept in VGPRs
    short8 bq[8];
    {
        const short* p = wq + i_g*8192 + (nt*16 + lo16)*256 + quad*8;
        #pragma unroll
        for (int kk=0;kk<8;kk++) bq[kk] = *(const short8*)(p + kk*32);
    }

    // B1 thread mapping: row covers (i, s_local), tg covers 8 t's
    int row = tid >> 2, tg = tid & 3;
    int s_b1 = row & 31, i_b1 = row >> 5;

    float4v acc[16];
    #pragma unroll
    for (int m=0;m<16;m++) acc[m] = (float4v){0.f,0.f,0.f,0.f};
    float D8[8], N8[8];
    #pragma unroll
    for (int u=0;u<8;u++){ D8[u]=0.f; N8[u]=0.f; }

    const short* ctxTj = ctxT + (size_t)j * (320*256);
    int s_row = tid >> 3, c0 = (tid & 7)*32;   // staging assignment

    for (int tile = 0; tile < 10; tile++) {
        // ---- stage global -> LDS ctx_sc
        {
            const short* g = ctxTj + (tile*32 + s_row)*256 + c0;
            short8 v0 = *(const short8*)(g);
            short8 v1 = *(const short8*)(g+8);
            short8 v2 = *(const short8*)(g+16);
            short8 v3 = *(const short8*)(g+24);
            short* d = ctx_sc + s_row*264 + c0;
            *(short8*)(d)    = v0; *(short8*)(d+8)  = v1;
            *(short8*)(d+16) = v2; *(short8*)(d+24) = v3;
        }
        __syncthreads();
        // ---- transpose ctx_sc -> ctx_cs (thread = one c column)
        {
            int c = tid;
            short8 t0, t1, t2, t3;
            #pragma unroll
            for (int s=0;s<8;s++)  t0[s] = ctx_sc[s*264 + c];
            #pragma unroll
            for (int s=0;s<8;s++)  t1[s] = ctx_sc[(8+s)*264 + c];
            #pragma unroll
            for (int s=0;s<8;s++)  t2[s] = ctx_sc[(16+s)*264 + c];
            #pragma unroll
            for (int s=0;s<8;s++)  t3[s] = ctx_sc[(24+s)*264 + c];
            short* d = ctx_cs + c*40;
            *(short8*)(d)    = t0; *(short8*)(d+8)  = t1;
            *(short8*)(d+16) = t2; *(short8*)(d+24) = t3;
        }
        // ---- scores MFMA: wave (i_l, nt): 2 Mtiles x 8 k-steps
        {
            #pragma unroll
            for (int mt=0; mt<2; mt++) {
                float4v sacc = {0.f,0.f,0.f,0.f};
                const short* ap = ctx_sc + (mt*16 + lo16)*264 + quad*8;
                #pragma unroll
                for (int kk=0;kk<8;kk++)
                    sacc = mfma_bf16(*(const short8*)(ap + kk*32), bq[kk], sacc);
                float* sp = scoresL + i_l*1152 + (mt*16 + quad*4)*36 + nt*16 + lo16;
                #pragma unroll
                for (int r=0;r<4;r++) sp[r*36] = sacc[r];
            }
        }
        __syncthreads();
        // ---- softmax over t (local), e = exp(G1*a1), accumulate D/num
        {
            int sg = tile*32 + s_b1;
            const float* sp = scoresL + i_b1*1152 + s_b1*36 + tg*8;
            float4 f0 = *(const float4*)(sp);
            float4 f1 = *(const float4*)(sp + 4);
            float sc[8] = {f0.x,f0.y,f0.z,f0.w,f1.x,f1.y,f1.z,f1.w};
            float mx = sc[0];
            #pragma unroll
            for (int u=1;u<8;u++) mx = fmaxf(mx, sc[u]);
            mx = fmaxf(mx, __shfl_xor(mx,1));
            mx = fmaxf(mx, __shfl_xor(mx,2));
            float es[8], sum = 0.f;
            #pragma unroll
            for (int u=0;u<8;u++){ es[u] = __expf(sc[u]-mx); sum += es[u]; }
            sum += __shfl_xor(sum,1);
            sum += __shfl_xor(sum,2);
            float rinv = 1.0f/sum;
            short* ep = eT + i_b1*1280 + (tg*8)*40 + s_b1;
            if (sg < 289) {
                #pragma unroll
                for (int u=0;u<8;u++) {
                    float e = __expf(G1c*es[u]*rinv);
                    D8[u] += e; N8[u] += e*sc[u];
                    ep[u*40] = f2bf(e);
                }
            } else {
                #pragma unroll
                for (int u=0;u<8;u++) ep[u*40] = 0;
            }
        }
        __syncthreads();
        // ---- wC MFMA: wave (i_l, nt): 16 Mtiles x K=32, acc in regs
        {
            const short* bp = eT + i_l*1280 + (nt*16 + lo16)*40 + quad*8;
            short8 bf = *(const short8*)(bp);
            #pragma unroll
            for (int mt=0;mt<16;mt++) {
                const short* ap = ctx_cs + (mt*16 + lo16)*40 + quad*8;
                acc[mt] = mfma_bf16(*(const short8*)(ap), bf, acc[mt]);
            }
        }
        __syncthreads();
    }

    // ---- reduce D/num over s lanes (bits 2..5 of lane)
    #pragma unroll
    for (int u=0;u<8;u++) {
        for (int o=4;o<64;o<<=1) {
            D8[u] += __shfl_xor(D8[u],o);
            N8[u] += __shfl_xor(N8[u],o);
        }
    }
    if ((lane>>2)==0) {
        #pragma unroll
        for (int u=0;u<8;u++) { Dp[wave][tg*8+u] = D8[u]; Np[wave][tg*8+u] = N8[u]; }
    }
    // ---- wn2 from acc regs: sum over 16 Mtiles x 4 regs, reduce over quads
    {
        float ss = 0.f;
        #pragma unroll
        for (int mt=0;mt<16;mt++)
            #pragma unroll
            for (int r=0;r<4;r++){ float v = acc[mt][r]; ss += v*v; }
        ss += __shfl_xor(ss,16);
        ss += __shfl_xor(ss,32);
        if (quad==0) wn2L[i_l][nt*16 + lo16] = ss;
    }
    __syncthreads();

    // ---- epilogue: cos, logsumexp over t -> sim
    if (tid < 64) {
        int i_f = tid >> 5, t = tid & 31;
        float D = Dp[i_f*2][t] + Dp[i_f*2+1][t];
        float N = Np[i_f*2][t] + Np[i_f*2+1][t];
        float w2 = wn2L[i_f][t];
        int i_gf = ip*2 + i_f;
        float qv = W[WS_QN + i_gf*32 + t];
        float numS = N/D;
        float wnS = sqrtf(w2)/D;
        float v = G2c * (numS / fmaxf(qv*wnS, EPSF));
        float mx = v;
        for (int o=1;o<32;o<<=1) mx = fmaxf(mx, __shfl_xor(mx,o));
        float e = __expf(v-mx);
        for (int o=1;o<32;o<<=1) e += __shfl_xor(e,o);
        if (t==0) W[WS_SIM + i_gf*64 + j] = mx + __logf(e);
    }
}

// ---------------------------------------------------------------------------
// s0 = G3*cn@rn^T, s2 = G3*rn@ran^T   (grid 64, one i per block)
// ---------------------------------------------------------------------------
__global__ __launch_bounds__(256) void smat_kernel(float* __restrict__ W)
{
    int i = blockIdx.x, tid = threadIdx.x, lane = tid&63, wave = tid>>6;
    __shared__ float a0[256], a1[256];
    __shared__ float part[2][64][4];
    a0[tid] = W[WS_CN + i*256 + tid];
    a1[tid] = W[WS_RN + i*256 + tid];
    __syncthreads();
    const float* B0 = W + WS_RN;
    const float* B1 = W + WS_RAN;
    float av0 = a0[tid], av1 = a1[tid];
    for (int jj = 0; jj < 64; jj++) {
        float v0 = av0 * B0[jj*256 + tid];
        float v1 = av1 * B1[jj*256 + tid];
        for (int o=1;o<64;o<<=1){ v0 += __shfl_xor(v0,o); v1 += __shfl_xor(v1,o); }
        if (lane==0){ part[0][jj][wave]=v0; part[1][jj][wave]=v1; }
    }
    __syncthreads();
    if (tid < 128) {
        int mat = tid>>6, jj = tid&63;
        float s = part[mat][jj][0]+part[mat][jj][1]+part[mat][jj][2]+part[mat][jj][3];
        W[(mat? WS_S2 : WS_S0) + i*64 + jj] = G3c * s;
    }
}

// ---------------------------------------------------------------------------
// Final: all cross-entropies -> d_out[7]
// ---------------------------------------------------------------------------
__global__ __launch_bounds__(256) void final_kernel(
    const int* __restrict__ labels, float* __restrict__ W, float* __restrict__ out)
{
    int tid = threadIdx.x;
    __shared__ float cearr[6][64];
    __shared__ float cemoco[128];

    if (tid < 128) {
        int mu = tid>>6, r = tid&63;
        float mm = -1e30f, ss = 0.f;
        for (int ch=0; ch<64; ch++) {
            float om = W[WS_PM + (mu*64+r)*64 + ch];
            float os = W[WS_PS + (mu*64+r)*64 + ch];
            float nm = fmaxf(mm, om);
            ss = ss*__expf(mm-nm) + os*__expf(om-nm);
            mm = nm;
        }
        const float* A  = W + (mu? WS_RN : WS_CN) + r*256;
        const float* Bv = W + (mu? WS_CAN : WS_RAN) + r*256;
        float dot = 0.f;
        for (int c=0;c<256;c++) dot += A[c]*Bv[c];
        float v0 = dot*INV_T;
        float nm = fmaxf(mm, v0);
        float S = ss*__expf(mm-nm) + __expf(v0-nm);
        cemoco[tid] = nm + __logf(S) - v0;
    }

    for (int pass=0; pass<2; pass++) {
        int cfg = pass*4 + (tid>>6);
        int row = tid&63;
        if (cfg < 6) {
            const float* mat; float scale; int colMajor;
            if (cfg==0){ mat=W+WS_SIM; scale=G3c; colMajor=1; }
            else if (cfg==1){ mat=W+WS_SIM; scale=G3c; colMajor=0; }
            else if (cfg==2){ mat=W+WS_S0; scale=1.f; colMajor=0; }
            else if (cfg==3){ mat=W+WS_S0; scale=1.f; colMajor=1; }
            else if (cfg==4){ mat=W+WS_S2; scale=1.f; colMajor=0; }
            else            { mat=W+WS_S2; scale=1.f; colMajor=1; }
            float mx = -1e30f;
            for (int x=0;x<64;x++) {
                float v = (colMajor? mat[x*64+row] : mat[row*64+x])*scale;
                mx = fmaxf(mx, v);
            }
            float se = 0.f;
            for (int x=0;x<64;x++) {
                float v = (colMajor? mat[x*64+row] : mat[row*64+x])*scale;
                se += __expf(v-mx);
            }
            int lbl = labels[row];
            float diag = (colMajor? mat[lbl*64+row] : mat[row*64+lbl])*scale;
            cearr[cfg][row] = mx + __logf(se) - diag;
        }
    }
    __syncthreads();

    if (tid < 7) {
        float r;
        if (tid == 4) {
            float s0=0.f, s1=0.f;
            for (int k=0;k<64;k++){ s0 += cemoco[k]; s1 += cemoco[64+k]; }
            r = (s0/64.f + s1/64.f)*0.5f;
        } else {
            int cfg = (tid < 4) ? tid : tid - 1;
            float s = 0.f;
            for (int k=0;k<64;k++) s += cearr[cfg][k];
            r = s/64.f;
        }
        out[tid] = r;
    }
}

// ---------------------------------------------------------------------------
extern "C" void kernel_launch(void* const* d_in, const int* in_sizes, int n_in,
                              void* d_out, int out_size, void* d_ws, size_t ws_size,
                              hipStream_t stream)
{
    const float* cnn   = (const float*)d_in[0];
    const float* rnn   = (const float*)d_in[1];
    const float* img   = (const float*)d_in[2];
    const float* wemb  = (const float*)d_in[3];
    const float* cnnA  = (const float*)d_in[4];
    const float* rnnA  = (const float*)d_in[5];
    const float* queue   = (const float*)d_in[6];
    const float* queueIm = (const float*)d_in[7];
    const int*   labels  = (const int*)d_in[9];
    float* W   = (float*)d_ws;
    float* out = (float*)d_out;

    prep_kernel<<<3648, 256, 0, stream>>>(cnn, rnn, img, wemb, cnnA, rnnA, W);
    moco_kernel<<<256, 256, 0, stream>>>(queue, queueIm, W);
    attn_kernel<<<2048, 256, 0, stream>>>(W);
    smat_kernel<<<64, 256, 0, stream>>>(W);
    final_kernel<<<1, 256, 0, stream>>>(labels, W, out);
}

// Round 3
// 319.919 us; speedup vs baseline: 1.4301x; 1.2103x over previous
//
#include <hip/hip_runtime.h>
#include <hip/hip_bf16.h>
#include <math.h>

// Problem constants
#define BB   64
#define TT   32
#define CC   256
#define KK   16384
#define G1c  4.0f
#define G2c  5.0f
#define G3c  10.0f
#define INV_T 20.0f
#define EPSF 1e-8f

// Workspace layout (floats)
#define WS_SIM 0
#define WS_S0  4096
#define WS_S2  8192
#define WS_CN  12288
#define WS_RN  28672
#define WS_CAN 45056
#define WS_RAN 61440
#define WS_QN  77824
#define WS_PM  79872                 // [2][64 ch][64 row]
#define WS_PS  (WS_PM + 8192)
#define WS_CNT  (WS_PS + 8192)      // [256][64] transposed codes
#define WS_RNT  (WS_CNT + 16384)
#define WS_CANT (WS_RNT + 16384)
#define WS_RANT (WS_CANT + 16384)
#define WS_F32_TOTAL (WS_RANT + 16384)

#define CTXT_ELEMS (64*320*256)    // ctxT[j][s(320 pad)][c] bf16
#define WQ_ELEMS   (64*32*256)     // wq[i][t][c] bf16

// LDS strides (in elements) chosen so stride-in-dwords ≡ 2 mod 4
// (gcd with 32 banks = 2 -> 16 distinct even banks; b64 ops -> no conflicts)
#define SC_STR 260   // ctx_sc rows (shorts): 130 dwords
#define CS_STR 36    // ctx_cs rows (shorts): 18 dwords
#define SL_STR 34    // scoresL rows (floats)
#define ET_STR 36    // eT rows (shorts)

typedef __attribute__((ext_vector_type(8))) short short8;
typedef __attribute__((ext_vector_type(4))) short short4v;
typedef __attribute__((ext_vector_type(4))) float float4v;
typedef __attribute__((ext_vector_type(2))) float float2v;

__device__ __forceinline__ float4v mfma_bf16(short8 a, short8 b, float4v c) {
    return __builtin_amdgcn_mfma_f32_16x16x32_bf16(a, b, c, 0, 0, 0);
}

__device__ __forceinline__ short f2bf(float f) {
    union { float f; unsigned u; } x; x.f = f;
    unsigned r = x.u + 0x7FFFu + ((x.u >> 16) & 1u);
    return (short)(r >> 16);
}

// LDS 8-short load as 2 x b64 (rows are 8B-aligned, not 16B)
__device__ __forceinline__ short8 ld8(const short* p) {
    short4v lo = *(const short4v*)p;
    short4v hi = *(const short4v*)(p + 4);
    short8 r = {lo[0],lo[1],lo[2],lo[3],hi[0],hi[1],hi[2],hi[3]};
    return r;
}

// ---------------------------------------------------------------------------
// Prep: normalize codes (+transposed copies), word norms, bf16 ctxT + wq
// grid: [0,256) codes | [256,2304) qn | [2304,3584) ctxT | [3584,3648) wq
// ---------------------------------------------------------------------------
__global__ __launch_bounds__(256) void prep_kernel(
    const float* __restrict__ cnn, const float* __restrict__ rnn,
    const float* __restrict__ img, const float* __restrict__ wemb,
    const float* __restrict__ cnnA, const float* __restrict__ rnnA,
    float* __restrict__ W)
{
    int bid = blockIdx.x, tid = threadIdx.x;
    short* B16 = (short*)(W + WS_F32_TOTAL);
    short* ctxT = B16;
    short* wq   = B16 + CTXT_ELEMS;

    if (bid < 256) {
        int mat = bid >> 6, row = bid & 63;
        const float* src = (mat==0)? cnn : (mat==1)? rnn : (mat==2)? cnnA : rnnA;
        float* dst  = W + ((mat==0)? WS_CN  : (mat==1)? WS_RN  : (mat==2)? WS_CAN  : WS_RAN);
        float* dstT = W + ((mat==0)? WS_CNT : (mat==1)? WS_RNT : (mat==2)? WS_CANT : WS_RANT);
        float v = src[row*256 + tid];
        float ss = v*v;
        for (int o=1;o<64;o<<=1) ss += __shfl_xor(ss,o);
        __shared__ float sc[4];
        if ((tid&63)==0) sc[tid>>6] = ss;
        __syncthreads();
        float tot = sc[0]+sc[1]+sc[2]+sc[3];
        float inv = 1.0f / fmaxf(sqrtf(tot), EPSF);
        float nv = v*inv;
        dst[row*256+tid] = nv;
        dstT[tid*64+row] = nv;
    } else if (bid < 2304) {
        int b2 = bid - 256; int i = b2 >> 5, t = b2 & 31;
        float v = wemb[(i*32 + t)*256 + tid];
        float ss = v*v;
        for (int o=1;o<64;o<<=1) ss += __shfl_xor(ss,o);
        __shared__ float sc2[4];
        if ((tid&63)==0) sc2[tid>>6] = ss;
        __syncthreads();
        if (tid==0) W[WS_QN + i*32 + t] = sqrtf(sc2[0]+sc2[1]+sc2[2]+sc2[3]);
    } else if (bid < 3584) {
        // ctxT[j][s][c] bf16, s padded to 320 (zeros for s>=289)
        int b3 = bid - 2304; int j = b3 / 20, mt = b3 % 20, s0 = mt*16;
        __shared__ float tile[16*257];
        for (int idx = tid; idx < 4096; idx += 256) {
            int c = idx >> 4, sl = idx & 15, s = s0 + sl;
            float v = (s < 289) ? img[((size_t)(j*256 + c))*289 + s] : 0.0f;
            tile[sl*257 + c] = v;
        }
        __syncthreads();
        for (int idx = tid; idx < 4096; idx += 256) {
            int orr = idx >> 8, c = idx & 255;
            ctxT[((size_t)(j*320 + s0 + orr))*256 + c] = f2bf(tile[orr*257 + c]);
        }
    } else {
        for (int idx = (bid-3584)*256 + tid; idx < WQ_ELEMS; idx += 64*256) {
            wq[idx] = f2bf(wemb[idx]);
        }
    }
}

// ---------------------------------------------------------------------------
// MoCo: grid 256 = mu(2) x rg(2: 32 rows) x ch(64: 256 cols).
// code rows cached in LDS; queue read 2x total. PM/PS stored [mu][ch][row].
// ---------------------------------------------------------------------------
__global__ __launch_bounds__(256) void moco_kernel(
    const float* __restrict__ queue, const float* __restrict__ queueIm,
    float* __restrict__ W)
{
    int bid = blockIdx.x, tid = threadIdx.x;
    int mu = bid >> 7, rg = (bid >> 6) & 1, ch = bid & 63;
    const float* Q = mu ? queueIm : queue;
    const float* code = W + (mu ? WS_RN : WS_CN) + rg*8192;
    __shared__ float code_l[8192];   // 32 rows x 256
    for (int idx = tid; idx < 8192; idx += 256)
        code_l[idx] = code[idx];
    __syncthreads();

    int col = ch*256 + tid;
    float dots[32];
    #pragma unroll
    for (int r=0;r<32;r++) dots[r] = 0.f;

    for (int c4 = 0; c4 < 64; c4++) {
        float q0 = Q[(size_t)(c4*4+0)*KK + col];
        float q1 = Q[(size_t)(c4*4+1)*KK + col];
        float q2 = Q[(size_t)(c4*4+2)*KK + col];
        float q3 = Q[(size_t)(c4*4+3)*KK + col];
        #pragma unroll
        for (int r=0;r<32;r++) {
            const float4 cv = *(const float4*)&code_l[r*256 + c4*4];
            dots[r] += cv.x*q0 + cv.y*q1 + cv.z*q2 + cv.w*q3;
        }
    }

    __shared__ float redm[4][32], reds[4][32];
    int lane = tid&63, wave = tid>>6;
    for (int r=0;r<32;r++) {
        float m = dots[r]*INV_T, s = 1.0f;
        for (int o=1;o<64;o<<=1) {
            float om = __shfl_xor(m,o), os = __shfl_xor(s,o);
            float nm = fmaxf(m,om);
            s = s*__expf(m-nm) + os*__expf(om-nm);
            m = nm;
        }
        if (lane==0){ redm[wave][r]=m; reds[wave][r]=s; }
    }
    __syncthreads();
    if (tid < 32) {
        float m = redm[0][tid], s = reds[0][tid];
        for (int w=1;w<4;w++) {
            float om = redm[w][tid], os = reds[w][tid];
            float nm = fmaxf(m,om);
            s = s*__expf(m-nm) + os*__expf(om-nm);
            m = nm;
        }
        int row = rg*32 + tid;
        W[WS_PM + mu*4096 + ch*64 + row] = m;
        W[WS_PS + mu*4096 + ch*64 + row] = s;
    }
}

// ---------------------------------------------------------------------------
// Attention: block = (j, i-pair). Stream s in 32-tiles with register prefetch.
// Conflict-free LDS strides (dword stride ≡ 2 mod 4) + b64 accesses.
// ---------------------------------------------------------------------------
__global__ __launch_bounds__(256, 3) void attn_kernel(float* __restrict__ W)
{
    __shared__ short ctx_sc[32*SC_STR];     // [s][c]      16640 B
    __shared__ short ctx_cs[256*CS_STR];    // [c][s]      18432 B
    __shared__ float scoresL[2*32*SL_STR];  // [i][s][t]    8704 B
    __shared__ short eT[2*32*ET_STR];       // [i][t][s]    4608 B
    __shared__ float Dp[4][32], Np[4][32], wn2L[2][32];

    const short* B16 = (const short*)(W + WS_F32_TOTAL);
    const short* ctxT = B16;
    const short* wq   = B16 + CTXT_ELEMS;

    int bid = blockIdx.x;
    int j = bid >> 5, ip = bid & 31;
    int tid = threadIdx.x, lane = tid & 63, wave = tid >> 6;
    int lo16 = lane & 15, quad = lane >> 4;
    int i_l = wave >> 1, nt = wave & 1;       // wave -> (i_local, t-half)
    int i_g = ip*2 + i_l;

    // wq fragments for this wave's (i, t-half), kept in VGPRs
    short8 bq[8];
    {
        const short* p = wq + i_g*8192 + (nt*16 + lo16)*256 + quad*8;
        #pragma unroll
        for (int kk=0;kk<8;kk++) bq[kk] = *(const short8*)(p + kk*32);
    }

    // B1 thread mapping
    int row = tid >> 2, tg = tid & 3;
    int s_b1 = row & 31, i_b1 = row >> 5;

    float4v acc[16];
    #pragma unroll
    for (int m=0;m<16;m++) acc[m] = (float4v){0.f,0.f,0.f,0.f};
    float D8[8], N8[8];
    #pragma unroll
    for (int u=0;u<8;u++){ D8[u]=0.f; N8[u]=0.f; }

    const short* ctxTj = ctxT + (size_t)j * (320*256);
    int s_row = tid >> 3, c0 = (tid & 7)*32;   // staging assignment

    // prefetch tile 0
    short8 pf[4], pfn[4];
    {
        const short* g = ctxTj + s_row*256 + c0;
        #pragma unroll
        for (int m=0;m<4;m++) pf[m] = *(const short8*)(g + m*8);
    }

    for (int tile = 0; tile < 10; tile++) {
        // ---- stage prefetched regs -> LDS ctx_sc (b64 writes)
        {
            short* d = ctx_sc + s_row*SC_STR + c0;
            #pragma unroll
            for (int k=0;k<8;k++) {
                short4v w = { pf[k>>1][(k&1)*4+0], pf[k>>1][(k&1)*4+1],
                              pf[k>>1][(k&1)*4+2], pf[k>>1][(k&1)*4+3] };
                *(short4v*)(d + k*4) = w;
            }
        }
        __syncthreads();
        // ---- issue next tile's global loads (overlaps with compute below)
        if (tile < 9) {
            const short* g = ctxTj + ((tile+1)*32 + s_row)*256 + c0;
            #pragma unroll
            for (int m=0;m<4;m++) pfn[m] = *(const short8*)(g + m*8);
        }
        // ---- transpose ctx_sc -> ctx_cs (scalar reads, b64 writes)
        {
            short v[32];
            #pragma unroll
            for (int s=0;s<32;s++) v[s] = ctx_sc[s*SC_STR + tid];
            short* dd = ctx_cs + tid*CS_STR;
            #pragma unroll
            for (int k=0;k<8;k++) {
                short4v w = { v[4*k], v[4*k+1], v[4*k+2], v[4*k+3] };
                *(short4v*)(dd + k*4) = w;
            }
        }
        // ---- scores MFMA: wave (i_l, nt): 2 Mtiles x 8 k-steps
        {
            #pragma unroll
            for (int mt=0; mt<2; mt++) {
                float4v sacc = {0.f,0.f,0.f,0.f};
                const short* ap = ctx_sc + (mt*16 + lo16)*SC_STR + quad*8;
                #pragma unroll
                for (int kk=0;kk<8;kk++)
                    sacc = mfma_bf16(ld8(ap + kk*32), bq[kk], sacc);
                float* sp = scoresL + i_l*(32*SL_STR) + (mt*16 + quad*4)*SL_STR + nt*16 + lo16;
                #pragma unroll
                for (int r=0;r<4;r++) sp[r*SL_STR] = sacc[r];
            }
        }
        __syncthreads();
        // ---- softmax over t (local), e = exp(G1*a1), accumulate D/num
        {
            int sg = tile*32 + s_b1;
            const float* sp = scoresL + i_b1*(32*SL_STR) + s_b1*SL_STR + tg*8;
            float2v g0 = *(const float2v*)(sp);
            float2v g1 = *(const float2v*)(sp+2);
            float2v g2 = *(const float2v*)(sp+4);
            float2v g3 = *(const float2v*)(sp+6);
            float sc[8] = {g0[0],g0[1],g1[0],g1[1],g2[0],g2[1],g3[0],g3[1]};
            float mx = sc[0];
            #pragma unroll
            for (int u=1;u<8;u++) mx = fmaxf(mx, sc[u]);
            mx = fmaxf(mx, __shfl_xor(mx,1));
            mx = fmaxf(mx, __shfl_xor(mx,2));
            float es[8], sum = 0.f;
            #pragma unroll
            for (int u=0;u<8;u++){ es[u] = __expf(sc[u]-mx); sum += es[u]; }
            sum += __shfl_xor(sum,1);
            sum += __shfl_xor(sum,2);
            float rinv = 1.0f/sum;
            short* ep = eT + i_b1*(32*ET_STR) + (tg*8)*ET_STR + s_b1;
            if (sg < 289) {
                #pragma unroll
                for (int u=0;u<8;u++) {
                    float e = __expf(G1c*es[u]*rinv);
                    D8[u] += e; N8[u] += e*sc[u];
                    ep[u*ET_STR] = f2bf(e);
                }
            } else {
                #pragma unroll
                for (int u=0;u<8;u++) ep[u*ET_STR] = 0;
            }
        }
        __syncthreads();
        // ---- wC MFMA: wave (i_l, nt): 16 Mtiles x K=32, acc in regs
        {
            const short* bp = eT + i_l*(32*ET_STR) + (nt*16 + lo16)*ET_STR + quad*8;
            short8 bf = ld8(bp);
            #pragma unroll
            for (int mt=0;mt<16;mt++) {
                const short* ap = ctx_cs + (mt*16 + lo16)*CS_STR + quad*8;
                acc[mt] = mfma_bf16(ld8(ap), bf, acc[mt]);
            }
        }
        __syncthreads();
        if (tile < 9) {
            #pragma unroll
            for (int m=0;m<4;m++) pf[m] = pfn[m];
        }
    }

    // ---- reduce D/num over s lanes (bits 2..5 of lane)
    #pragma unroll
    for (int u=0;u<8;u++) {
        for (int o=4;o<64;o<<=1) {
            D8[u] += __shfl_xor(D8[u],o);
            N8[u] += __shfl_xor(N8[u],o);
        }
    }
    if ((lane>>2)==0) {
        #pragma unroll
        for (int u=0;u<8;u++) { Dp[wave][tg*8+u] = D8[u]; Np[wave][tg*8+u] = N8[u]; }
    }
    // ---- wn2 from acc regs
    {
        float ss = 0.f;
        #pragma unroll
        for (int mt=0;mt<16;mt++)
            #pragma unroll
            for (int r=0;r<4;r++){ float v = acc[mt][r]; ss += v*v; }
        ss += __shfl_xor(ss,16);
        ss += __shfl_xor(ss,32);
        if (quad==0) wn2L[i_l][nt*16 + lo16] = ss;
    }
    __syncthreads();

    // ---- epilogue: cos, logsumexp over t -> sim
    if (tid < 64) {
        int i_f = tid >> 5, t = tid & 31;
        float D = Dp[i_f*2][t] + Dp[i_f*2+1][t];
        float N = Np[i_f*2][t] + Np[i_f*2+1][t];
        float w2 = wn2L[i_f][t];
        int i_gf = ip*2 + i_f;
        float qv = W[WS_QN + i_gf*32 + t];
        float numS = N/D;
        float wnS = sqrtf(w2)/D;
        float v = G2c * (numS / fmaxf(qv*wnS, EPSF));
        float mx = v;
        for (int o=1;o<32;o<<=1) mx = fmaxf(mx, __shfl_xor(mx,o));
        float e = __expf(v-mx);
        for (int o=1;o<32;o<<=1) e += __shfl_xor(e,o);
        if (t==0) W[WS_SIM + i_gf*64 + j] = mx + __logf(e);
    }
}

// ---------------------------------------------------------------------------
// s0 = G3*cn@rn^T, s2 = G3*rn@ran^T   (grid 64, one i per block)
// ---------------------------------------------------------------------------
__global__ __launch_bounds__(256) void smat_kernel(float* __restrict__ W)
{
    int i = blockIdx.x, tid = threadIdx.x, lane = tid&63, wave = tid>>6;
    __shared__ float a0[256], a1[256];
    __shared__ float part[2][64][4];
    a0[tid] = W[WS_CN + i*256 + tid];
    a1[tid] = W[WS_RN + i*256 + tid];
    __syncthreads();
    const float* B0 = W + WS_RN;
    const float* B1 = W + WS_RAN;
    float av0 = a0[tid], av1 = a1[tid];
    for (int jj = 0; jj < 64; jj++) {
        float v0 = av0 * B0[jj*256 + tid];
        float v1 = av1 * B1[jj*256 + tid];
        for (int o=1;o<64;o<<=1){ v0 += __shfl_xor(v0,o); v1 += __shfl_xor(v1,o); }
        if (lane==0){ part[0][jj][wave]=v0; part[1][jj][wave]=v1; }
    }
    __syncthreads();
    if (tid < 128) {
        int mat = tid>>6, jj = tid&63;
        float s = part[mat][jj][0]+part[mat][jj][1]+part[mat][jj][2]+part[mat][jj][3];
        W[(mat? WS_S2 : WS_S0) + i*64 + jj] = G3c * s;
    }
}

// ---------------------------------------------------------------------------
// Final: all cross-entropies -> d_out[7].  64x64 mats cached in LDS (stride
// 65); moco partial merge reads coalesced [ch][row] layout; dots use the
// transposed code copies.
// ---------------------------------------------------------------------------
__global__ __launch_bounds__(256) void final_kernel(
    const int* __restrict__ labels, float* __restrict__ W, float* __restrict__ out)
{
    int tid = threadIdx.x;
    __shared__ float mats[3][64][65];      // SIM, S0, S2
    __shared__ float mmL[2][4][64], ssL[2][4][64];
    __shared__ float cearr[6][64];
    __shared__ float cemoco[128];

    // load the three 64x64 matrices into LDS (coalesced)
    for (int idx = tid; idx < 3*4096; idx += 256) {
        int t = idx >> 12, rem = idx & 4095;
        const float* src = W + (t==0 ? WS_SIM : (t==1 ? WS_S0 : WS_S2));
        mats[t][rem>>6][rem&63] = src[rem];
    }

    // moco partial merge: thread (g, r) merges 16 ch-chunks (coalesced loads)
    {
        int g = tid >> 6, r = tid & 63;
        for (int mu=0; mu<2; mu++) {
            float m = -1e30f, s = 0.f;
            for (int k=0; k<16; k++) {
                int ch = g*16 + k;
                float om = W[WS_PM + mu*4096 + ch*64 + r];
                float os = W[WS_PS + mu*4096 + ch*64 + r];
                float nm = fmaxf(m, om);
                s = s*__expf(m-nm) + os*__expf(om-nm);
                m = nm;
            }
            mmL[mu][g][r] = m; ssL[mu][g][r] = s;
        }
    }
    __syncthreads();

    if (tid < 128) {
        int mu = tid>>6, r = tid&63;
        float m = mmL[mu][0][r], s = ssL[mu][0][r];
        for (int g=1; g<4; g++) {
            float om = mmL[mu][g][r], os = ssL[mu][g][r];
            float nm = fmaxf(m, om);
            s = s*__expf(m-nm) + os*__expf(om-nm);
            m = nm;
        }
        const float* AT = W + (mu ? WS_RNT : WS_CNT);
        const float* BT = W + (mu ? WS_CANT : WS_RANT);
        float dot = 0.f;
        for (int c=0; c<256; c++) dot += AT[c*64 + r]*BT[c*64 + r];
        float v0 = dot*INV_T;
        float nm = fmaxf(m, v0);
        float S = s*__expf(m-nm) + __expf(v0-nm);
        cemoco[tid] = nm + __logf(S) - v0;
    }

    for (int pass=0; pass<2; pass++) {
        int cfg = pass*4 + (tid>>6);
        int row = tid&63;
        if (cfg < 6) {
            int mi; float scale; int colMajor;
            if (cfg==0){ mi=0; scale=G3c; colMajor=1; }
            else if (cfg==1){ mi=0; scale=G3c; colMajor=0; }
            else if (cfg==2){ mi=1; scale=1.f; colMajor=0; }
            else if (cfg==3){ mi=1; scale=1.f; colMajor=1; }
            else if (cfg==4){ mi=2; scale=1.f; colMajor=0; }
            else            { mi=2; scale=1.f; colMajor=1; }
            float mx = -1e30f;
            for (int x=0;x<64;x++) {
                float v = (colMajor? mats[mi][x][row] : mats[mi][row][x])*scale;
                mx = fmaxf(mx, v);
            }
            float se = 0.f;
            for (int x=0;x<64;x++) {
                float v = (colMajor? mats[mi][x][row] : mats[mi][row][x])*scale;
                se += __expf(v-mx);
            }
            int lbl = labels[row];
            float diag = (colMajor? mats[mi][lbl][row] : mats[mi][row][lbl])*scale;
            cearr[cfg][row] = mx + __logf(se) - diag;
        }
    }
    __syncthreads();

    if (tid < 7) {
        float r;
        if (tid == 4) {
            float s0=0.f, s1=0.f;
            for (int k=0;k<64;k++){ s0 += cemoco[k]; s1 += cemoco[64+k]; }
            r = (s0/64.f + s1/64.f)*0.5f;
        } else {
            int cfg = (tid < 4) ? tid : tid - 1;
            float s = 0.f;
            for (int k=0;k<64;k++) s += cearr[cfg][k];
            r = s/64.f;
        }
        out[tid] = r;
    }
}

// ---------------------------------------------------------------------------
extern "C" void kernel_launch(void* const* d_in, const int* in_sizes, int n_in,
                              void* d_out, int out_size, void* d_ws, size_t ws_size,
                              hipStream_t stream)
{
    const float* cnn   = (const float*)d_in[0];
    const float* rnn   = (const float*)d_in[1];
    const float* img   = (const float*)d_in[2];
    const float* wemb  = (const float*)d_in[3];
    const float* cnnA  = (const float*)d_in[4];
    const float* rnnA  = (const float*)d_in[5];
    const float* queue   = (const float*)d_in[6];
    const float* queueIm = (const float*)d_in[7];
    const int*   labels  = (const int*)d_in[9];
    float* W   = (float*)d_ws;
    float* out = (float*)d_out;

    prep_kernel<<<3648, 256, 0, stream>>>(cnn, rnn, img, wemb, cnnA, rnnA, W);
    moco_kernel<<<256, 256, 0, stream>>>(queue, queueIm, W);
    attn_kernel<<<2048, 256, 0, stream>>>(W);
    smat_kernel<<<64, 256, 0, stream>>>(W);
    final_kernel<<<1, 256, 0, stream>>>(labels, W, out);
}

// Round 4
// 319.735 us; speedup vs baseline: 1.4309x; 1.0006x over previous
//
#include <hip/hip_runtime.h>
#include <hip/hip_bf16.h>
#include <math.h>

#define BB   64
#define TT   32
#define CC   256
#define KK   16384
#define G1c  4.0f
#define G2c  5.0f
#define G3c  10.0f
#define INV_T 20.0f
#define EPSF 1e-8f

// Workspace layout (floats)
#define WS_SIM 0
#define WS_S0  4096
#define WS_S2  8192
#define WS_CN  12288
#define WS_RN  28672
#define WS_CAN 45056
#define WS_RAN 61440
#define WS_QN  77824
#define WS_PM  79872                 // [2][64 ch][64 row]
#define WS_PS  (WS_PM + 8192)
#define WS_CNT  (WS_PS + 8192)      // [256][64] transposed codes
#define WS_RNT  (WS_CNT + 16384)
#define WS_CANT (WS_RNT + 16384)
#define WS_RANT (WS_CANT + 16384)
#define WS_F32_TOTAL (WS_RANT + 16384)

// bf16 arrays (shorts), after the f32 section
#define CTXT_ELEMS (64*320*256)    // ctxT[j][s(320)][c]
#define CTXC_ELEMS (64*256*320)    // ctxC[j][c][s(320)]
#define WQ_ELEMS   (64*32*256)     // wq[i][t][c]
#define CNRN_OFF   (CTXT_ELEMS + CTXC_ELEMS + WQ_ELEMS)  // [2][64][256]

typedef __attribute__((ext_vector_type(8))) short short8;
typedef __attribute__((ext_vector_type(4))) short short4v;
typedef __attribute__((ext_vector_type(4))) float float4v;
typedef __attribute__((ext_vector_type(2))) float float2v;

__device__ __forceinline__ float4v mfma_bf16(short8 a, short8 b, float4v c) {
    return __builtin_amdgcn_mfma_f32_16x16x32_bf16(a, b, c, 0, 0, 0);
}

__device__ __forceinline__ short f2bf(float f) {
    union { float f; unsigned u; } x; x.f = f;
    unsigned r = x.u + 0x7FFFu + ((x.u >> 16) & 1u);
    return (short)(r >> 16);
}

// LDS 8-short load as 2 x b64 (rows 8B-aligned)
__device__ __forceinline__ short8 ld8(const short* p) {
    short4v lo = *(const short4v*)p;
    short4v hi = *(const short4v*)(p + 4);
    short8 r = {lo[0],lo[1],lo[2],lo[3],hi[0],hi[1],hi[2],hi[3]};
    return r;
}

// ---------------------------------------------------------------------------
// Prep. grid: [0,256) codes | [256,320) qn | [320,1600) ctxT |
//             [1600,1984) ctxC | [1984,2048) wq
// ---------------------------------------------------------------------------
__global__ __launch_bounds__(256) void prep_kernel(
    const float* __restrict__ cnn, const float* __restrict__ rnn,
    const float* __restrict__ img, const float* __restrict__ wemb,
    const float* __restrict__ cnnA, const float* __restrict__ rnnA,
    float* __restrict__ W)
{
    int bid = blockIdx.x, tid = threadIdx.x;
    short* B16 = (short*)(W + WS_F32_TOTAL);
    short* ctxT = B16;
    short* ctxC = B16 + CTXT_ELEMS;
    short* wq   = B16 + CTXT_ELEMS + CTXC_ELEMS;
    short* cnrn = B16 + CNRN_OFF;

    if (bid < 256) {
        int mat = bid >> 6, row = bid & 63;
        const float* src = (mat==0)? cnn : (mat==1)? rnn : (mat==2)? cnnA : rnnA;
        float* dst  = W + ((mat==0)? WS_CN  : (mat==1)? WS_RN  : (mat==2)? WS_CAN  : WS_RAN);
        float* dstT = W + ((mat==0)? WS_CNT : (mat==1)? WS_RNT : (mat==2)? WS_CANT : WS_RANT);
        float v = src[row*256 + tid];
        float ss = v*v;
        for (int o=1;o<64;o<<=1) ss += __shfl_xor(ss,o);
        __shared__ float sc[4];
        if ((tid&63)==0) sc[tid>>6] = ss;
        __syncthreads();
        float tot = sc[0]+sc[1]+sc[2]+sc[3];
        float inv = 1.0f / fmaxf(sqrtf(tot), EPSF);
        float nv = v*inv;
        dst[row*256+tid] = nv;
        dstT[tid*64+row] = nv;
        if (mat < 2) cnrn[(mat*64+row)*256 + tid] = f2bf(nv);
    } else if (bid < 320) {
        // qn: one block per i; thread = (t, k-octet)
        int i = bid - 256;
        int t = tid >> 3, k = tid & 7;
        const float* wp = wemb + (i*32 + t)*256 + k*32;
        float ss = 0.f;
        for (int c=0;c<32;c++){ float v = wp[c]; ss += v*v; }
        ss += __shfl_xor(ss,1); ss += __shfl_xor(ss,2); ss += __shfl_xor(ss,4);
        if (k==0) W[WS_QN + i*32 + t] = sqrtf(ss);
    } else if (bid < 1600) {
        // ctxT[j][s][c], s padded to 320 with zeros
        int b3 = bid - 320; int j = b3 / 20, mt = b3 % 20, s0 = mt*16;
        __shared__ float tile[16*257];
        for (int idx = tid; idx < 4096; idx += 256) {
            int c = idx >> 4, sl = idx & 15, s = s0 + sl;
            float v = (s < 289) ? img[((size_t)(j*256 + c))*289 + s] : 0.0f;
            tile[sl*257 + c] = v;
        }
        __syncthreads();
        for (int idx = tid; idx < 4096; idx += 256) {
            int orr = idx >> 8, c = idx & 255;
            ctxT[((size_t)(j*320 + s0 + orr))*256 + c] = f2bf(tile[orr*257 + c]);
        }
    } else if (bid < 1984) {
        // ctxC[j][c][s], s padded to 320 with zeros
        for (size_t idx = (size_t)(bid-1600)*256 + tid; idx < (size_t)CTXC_ELEMS; idx += (size_t)384*256) {
            int s = (int)(idx % 320); size_t rem = idx / 320;
            int c = (int)(rem & 255); int jj = (int)(rem >> 8);
            float v = (s < 289) ? img[((size_t)(jj*256 + c))*289 + s] : 0.0f;
            ctxC[idx] = f2bf(v);
        }
    } else {
        for (int idx = (bid-1984)*256 + tid; idx < WQ_ELEMS; idx += 64*256) {
            wq[idx] = f2bf(wemb[idx]);
        }
    }
}

// ---------------------------------------------------------------------------
// MoCo via MFMA (A = code bf16 in regs, B = queue f32->bf16 on the fly)
// grid 192: [0,128) moco: mu = bid>>6, colblock = bid&63 (256 cols each);
//           [128,192) smat (s0/s2 matrices).
// ---------------------------------------------------------------------------
__global__ __launch_bounds__(256) void moco_smat_kernel(
    const float* __restrict__ queue, const float* __restrict__ queueIm,
    float* __restrict__ W)
{
    int bid = blockIdx.x, tid = threadIdx.x;
    int lane = tid & 63, wave = tid >> 6;

    if (bid >= 128) {
        // ---- smat: s0 = G3*cn@rn^T, s2 = G3*rn@ran^T
        int i = bid - 128;
        __shared__ float a0[256], a1[256];
        __shared__ float part[2][64][4];
        a0[tid] = W[WS_CN + i*256 + tid];
        a1[tid] = W[WS_RN + i*256 + tid];
        __syncthreads();
        const float* B0 = W + WS_RN;
        const float* B1v = W + WS_RAN;
        float av0 = a0[tid], av1 = a1[tid];
        for (int jj = 0; jj < 64; jj++) {
            float v0 = av0 * B0[jj*256 + tid];
            float v1 = av1 * B1v[jj*256 + tid];
            for (int o=1;o<64;o<<=1){ v0 += __shfl_xor(v0,o); v1 += __shfl_xor(v1,o); }
            if (lane==0){ part[0][jj][wave]=v0; part[1][jj][wave]=v1; }
        }
        __syncthreads();
        if (tid < 128) {
            int mat = tid>>6, jj = tid&63;
            float s = part[mat][jj][0]+part[mat][jj][1]+part[mat][jj][2]+part[mat][jj][3];
            W[(mat? WS_S2 : WS_S0) + i*64 + jj] = G3c * s;
        }
        return;
    }

    int mu = bid >> 6, cb = bid & 63;
    int col0 = cb*256;
    const float* Q = mu ? queueIm : queue;
    const short* Abf = (const short*)(W + WS_F32_TOTAL) + CNRN_OFF + mu*16384;
    int lo16 = lane & 15, quad = lane >> 4;

    // A fragments: rows mt*16+lo16, k = kk*32+quad*8
    short8 afr[4][8];
    #pragma unroll
    for (int mt=0;mt<4;mt++)
        #pragma unroll
        for (int kk=0;kk<8;kk++)
            afr[mt][kk] = *(const short8*)(Abf + (mt*16+lo16)*256 + kk*32 + quad*8);

    float m16[16], s16[16];
    #pragma unroll
    for (int u=0;u<16;u++){ m16[u] = -1e30f; s16[u] = 0.f; }

    for (int t4 = 0; t4 < 4; t4++) {
        int colb = col0 + (wave*4 + t4)*16;
        float4v acc[4];
        #pragma unroll
        for (int mt=0;mt<4;mt++) acc[mt] = (float4v){0.f,0.f,0.f,0.f};
        for (int ks = 0; ks < 8; ks++) {
            short8 bfr;
            #pragma unroll
            for (int jj=0;jj<8;jj++) {
                float bv = Q[(size_t)(ks*32 + quad*8 + jj)*KK + colb + lo16];
                bfr[jj] = f2bf(bv);
            }
            #pragma unroll
            for (int mt=0;mt<4;mt++) acc[mt] = mfma_bf16(afr[mt][ks], bfr, acc[mt]);
        }
        #pragma unroll
        for (int mt=0;mt<4;mt++)
            #pragma unroll
            for (int r=0;r<4;r++) {
                float v = acc[mt][r]*INV_T;
                int u = mt*4+r;
                float nm = fmaxf(m16[u], v);
                s16[u] = s16[u]*__expf(m16[u]-nm) + __expf(v-nm);
                m16[u] = nm;
            }
    }
    // reduce over the 16 col-lanes (lo16)
    #pragma unroll
    for (int u=0;u<16;u++) {
        #pragma unroll
        for (int o=1;o<16;o<<=1) {
            float om = __shfl_xor(m16[u],o), os = __shfl_xor(s16[u],o);
            float nm = fmaxf(m16[u],om);
            s16[u] = s16[u]*__expf(m16[u]-nm) + os*__expf(om-nm);
            m16[u] = nm;
        }
    }
    __shared__ float rm[4][64], rs[4][64];
    if (lo16 == 0) {
        #pragma unroll
        for (int u=0;u<16;u++) {
            int row = (u>>2)*16 + quad*4 + (u&3);
            rm[wave][row] = m16[u]; rs[wave][row] = s16[u];
        }
    }
    __syncthreads();
    if (tid < 64) {
        float m = rm[0][tid], s = rs[0][tid];
        for (int w=1;w<4;w++) {
            float om = rm[w][tid], os = rs[w][tid];
            float nm = fmaxf(m,om);
            s = s*__expf(m-nm) + os*__expf(om-nm);
            m = nm;
        }
        W[WS_PM + mu*4096 + cb*64 + tid] = m;
        W[WS_PS + mu*4096 + cb*64 + tid] = s;
    }
}

// ---------------------------------------------------------------------------
// Attention, two-phase. Block = (j, i-pair).
// Phase 1: stream s in 32-tiles; scores via MFMA with A-frags straight from
//   global ctxT (L2/L3-resident); softmax-t; e -> persistent eT (full s).
// Phase 2: wC as one K=320 MFMA GEMM, A-frags straight from global ctxC,
//   cmt split 4-ways over waves x 4 (i,nt) B-combos; only wn2 kept.
// ---------------------------------------------------------------------------
__global__ __launch_bounds__(256) void attn_kernel(float* __restrict__ W)
{
    __shared__ float scoresL[2][32][34];                  // 8704 B
    __shared__ __align__(16) short eT[2][32][324];        // 41472 B (162 dw stride)
    __shared__ float Dp[4][32], Np[4][32];
    __shared__ float wn2P[4][2][2][16];

    const short* B16 = (const short*)(W + WS_F32_TOTAL);
    const short* ctxT = B16;
    const short* ctxC = B16 + CTXT_ELEMS;
    const short* wq   = B16 + CTXT_ELEMS + CTXC_ELEMS;

    int bid = blockIdx.x;
    int j = bid >> 5, ip = bid & 31;
    int tid = threadIdx.x, lane = tid & 63, wave = tid >> 6;
    int lo16 = lane & 15, quad = lane >> 4;
    int i_l = wave >> 1, mt = wave & 1;       // phase-1 role: (i_local, m-tile)
    int i_g = ip*2 + i_l;

    // wq fragments for this wave's i, both t-halves
    short8 bq[2][8];
    {
        const short* p = wq + i_g*8192;
        #pragma unroll
        for (int nt2=0;nt2<2;nt2++)
            #pragma unroll
            for (int kk=0;kk<8;kk++)
                bq[nt2][kk] = *(const short8*)(p + (nt2*16+lo16)*256 + kk*32 + quad*8);
    }

    // B1 mapping
    int row = tid >> 2, tg = tid & 3;
    int s_b1 = row & 31, i_b1 = row >> 5;

    float D8[8], N8[8];
    #pragma unroll
    for (int u=0;u<8;u++){ D8[u]=0.f; N8[u]=0.f; }

    const short* ctxTj = ctxT + (size_t)j * (320*256);

    for (int tile = 0; tile < 10; tile++) {
        // ---- scores MFMA: A from global, both t-halves
        {
            float4v a0 = {0.f,0.f,0.f,0.f}, a1 = {0.f,0.f,0.f,0.f};
            const short* ar = ctxTj + (tile*32 + mt*16 + lo16)*256 + quad*8;
            #pragma unroll
            for (int kk=0;kk<8;kk++) {
                short8 a = *(const short8*)(ar + kk*32);
                a0 = mfma_bf16(a, bq[0][kk], a0);
                a1 = mfma_bf16(a, bq[1][kk], a1);
            }
            #pragma unroll
            for (int r=0;r<4;r++) {
                scoresL[i_l][mt*16+quad*4+r][lo16]    = a0[r];
                scoresL[i_l][mt*16+quad*4+r][16+lo16] = a1[r];
            }
        }
        __syncthreads();
        // ---- softmax over t, e = exp(G1*a1) -> eT, accumulate D/N
        {
            int sg = tile*32 + s_b1;
            const float* sp = &scoresL[i_b1][s_b1][tg*8];
            float2v g0 = *(const float2v*)(sp);
            float2v g1 = *(const float2v*)(sp+2);
            float2v g2 = *(const float2v*)(sp+4);
            float2v g3 = *(const float2v*)(sp+6);
            float sc[8] = {g0[0],g0[1],g1[0],g1[1],g2[0],g2[1],g3[0],g3[1]};
            float mx = sc[0];
            #pragma unroll
            for (int u=1;u<8;u++) mx = fmaxf(mx, sc[u]);
            mx = fmaxf(mx, __shfl_xor(mx,1));
            mx = fmaxf(mx, __shfl_xor(mx,2));
            float es[8], sum = 0.f;
            #pragma unroll
            for (int u=0;u<8;u++){ es[u] = __expf(sc[u]-mx); sum += es[u]; }
            sum += __shfl_xor(sum,1);
            sum += __shfl_xor(sum,2);
            float rinv = 1.0f/sum;
            if (sg < 289) {
                #pragma unroll
                for (int u=0;u<8;u++) {
                    float e = __expf(G1c*es[u]*rinv);
                    D8[u] += e; N8[u] += e*sc[u];
                    eT[i_b1][tg*8+u][sg] = f2bf(e);
                }
            } else {
                #pragma unroll
                for (int u=0;u<8;u++) eT[i_b1][tg*8+u][sg] = 0;
            }
        }
        __syncthreads();   // scoresL free for next tile
    }

    // ---- D/N partials
    #pragma unroll
    for (int u=0;u<8;u++) {
        for (int o=4;o<64;o<<=1) {
            D8[u] += __shfl_xor(D8[u],o);
            N8[u] += __shfl_xor(N8[u],o);
        }
    }
    if ((lane>>2)==0) {
        #pragma unroll
        for (int u=0;u<8;u++) { Dp[wave][tg*8+u] = D8[u]; Np[wave][tg*8+u] = N8[u]; }
    }

    // ---- phase 2: wC GEMM (K=320), A from global ctxC, 4 B-combos per wave
    {
        const short* ctxCj = ctxC + (size_t)j * (256*320);
        float4v wacc[4][4];
        #pragma unroll
        for (int cm=0;cm<4;cm++)
            #pragma unroll
            for (int cb2=0;cb2<4;cb2++) wacc[cm][cb2] = (float4v){0.f,0.f,0.f,0.f};
        for (int ks = 0; ks < 10; ks++) {
            short8 bfr[4];
            #pragma unroll
            for (int i2=0;i2<2;i2++)
                #pragma unroll
                for (int nt2=0;nt2<2;nt2++)
                    bfr[i2*2+nt2] = ld8(&eT[i2][nt2*16+lo16][ks*32 + quad*8]);
            #pragma unroll
            for (int cm=0;cm<4;cm++) {
                int c = (wave*4+cm)*16 + lo16;
                short8 a = *(const short8*)(ctxCj + c*320 + ks*32 + quad*8);
                #pragma unroll
                for (int cb2=0;cb2<4;cb2++)
                    wacc[cm][cb2] = mfma_bf16(a, bfr[cb2], wacc[cm][cb2]);
            }
        }
        #pragma unroll
        for (int cb2=0;cb2<4;cb2++) {
            float ss = 0.f;
            #pragma unroll
            for (int cm=0;cm<4;cm++)
                #pragma unroll
                for (int r=0;r<4;r++){ float v = wacc[cm][cb2][r]; ss += v*v; }
            ss += __shfl_xor(ss,16);
            ss += __shfl_xor(ss,32);
            if (quad==0) wn2P[wave][cb2>>1][cb2&1][lo16] = ss;
        }
    }
    __syncthreads();

    // ---- epilogue: cos, logsumexp over t -> sim
    if (tid < 64) {
        int i_f = tid >> 5, t = tid & 31;
        int nt2 = t >> 4, lo = t & 15;
        float w2 = wn2P[0][i_f][nt2][lo] + wn2P[1][i_f][nt2][lo]
                 + wn2P[2][i_f][nt2][lo] + wn2P[3][i_f][nt2][lo];
        float D = Dp[i_f*2][t] + Dp[i_f*2+1][t];
        float N = Np[i_f*2][t] + Np[i_f*2+1][t];
        int i_gf = ip*2 + i_f;
        float qv = W[WS_QN + i_gf*32 + t];
        float numS = N/D;
        float wnS = sqrtf(w2)/D;
        float v = G2c * (numS / fmaxf(qv*wnS, EPSF));
        float mx = v;
        for (int o=1;o<32;o<<=1) mx = fmaxf(mx, __shfl_xor(mx,o));
        float e = __expf(v-mx);
        for (int o=1;o<32;o<<=1) e += __shfl_xor(e,o);
        if (t==0) W[WS_SIM + i_gf*64 + j] = mx + __logf(e);
    }
}

// ---------------------------------------------------------------------------
// Final: all cross-entropies -> d_out[7]
// ---------------------------------------------------------------------------
__global__ __launch_bounds__(256) void final_kernel(
    const int* __restrict__ labels, float* __restrict__ W, float* __restrict__ out)
{
    int tid = threadIdx.x;
    __shared__ float mats[3][64][65];
    __shared__ float mmL[2][4][64], ssL[2][4][64];
    __shared__ float cearr[6][64];
    __shared__ float cemoco[128];

    for (int idx = tid; idx < 3*4096; idx += 256) {
        int t = idx >> 12, rem = idx & 4095;
        const float* src = W + (t==0 ? WS_SIM : (t==1 ? WS_S0 : WS_S2));
        mats[t][rem>>6][rem&63] = src[rem];
    }

    {
        int g = tid >> 6, r = tid & 63;
        for (int mu=0; mu<2; mu++) {
            float m = -1e30f, s = 0.f;
            for (int k=0; k<16; k++) {
                int ch = g*16 + k;
                float om = W[WS_PM + mu*4096 + ch*64 + r];
                float os = W[WS_PS + mu*4096 + ch*64 + r];
                float nm = fmaxf(m, om);
                s = s*__expf(m-nm) + os*__expf(om-nm);
                m = nm;
            }
            mmL[mu][g][r] = m; ssL[mu][g][r] = s;
        }
    }
    __syncthreads();

    if (tid < 128) {
        int mu = tid>>6, r = tid&63;
        float m = mmL[mu][0][r], s = ssL[mu][0][r];
        for (int g=1; g<4; g++) {
            float om = mmL[mu][g][r], os = ssL[mu][g][r];
            float nm = fmaxf(m, om);
            s = s*__expf(m-nm) + os*__expf(om-nm);
            m = nm;
        }
        const float* AT = W + (mu ? WS_RNT : WS_CNT);
        const float* BT = W + (mu ? WS_CANT : WS_RANT);
        float dot = 0.f;
        for (int c=0; c<256; c++) dot += AT[c*64 + r]*BT[c*64 + r];
        float v0 = dot*INV_T;
        float nm = fmaxf(m, v0);
        float S = s*__expf(m-nm) + __expf(v0-nm);
        cemoco[tid] = nm + __logf(S) - v0;
    }

    for (int pass=0; pass<2; pass++) {
        int cfg = pass*4 + (tid>>6);
        int row = tid&63;
        if (cfg < 6) {
            int mi; float scale; int colMajor;
            if (cfg==0){ mi=0; scale=G3c; colMajor=1; }
            else if (cfg==1){ mi=0; scale=G3c; colMajor=0; }
            else if (cfg==2){ mi=1; scale=1.f; colMajor=0; }
            else if (cfg==3){ mi=1; scale=1.f; colMajor=1; }
            else if (cfg==4){ mi=2; scale=1.f; colMajor=0; }
            else            { mi=2; scale=1.f; colMajor=1; }
            float mx = -1e30f;
            for (int x=0;x<64;x++) {
                float v = (colMajor? mats[mi][x][row] : mats[mi][row][x])*scale;
                mx = fmaxf(mx, v);
            }
            float se = 0.f;
            for (int x=0;x<64;x++) {
                float v = (colMajor? mats[mi][x][row] : mats[mi][row][x])*scale;
                se += __expf(v-mx);
            }
            int lbl = labels[row];
            float diag = (colMajor? mats[mi][lbl][row] : mats[mi][row][lbl])*scale;
            cearr[cfg][row] = mx + __logf(se) - diag;
        }
    }
    __syncthreads();

    if (tid < 7) {
        float r;
        if (tid == 4) {
            float s0=0.f, s1=0.f;
            for (int k=0;k<64;k++){ s0 += cemoco[k]; s1 += cemoco[64+k]; }
            r = (s0/64.f + s1/64.f)*0.5f;
        } else {
            int cfg = (tid < 4) ? tid : tid - 1;
            float s = 0.f;
            for (int k=0;k<64;k++) s += cearr[cfg][k];
            r = s/64.f;
        }
        out[tid] = r;
    }
}

// ---------------------------------------------------------------------------
extern "C" void kernel_launch(void* const* d_in, const int* in_sizes, int n_in,
                              void* d_out, int out_size, void* d_ws, size_t ws_size,
                              hipStream_t stream)
{
    const float* cnn   = (const float*)d_in[0];
    const float* rnn   = (const float*)d_in[1];
    const float* img   = (const float*)d_in[2];
    const float* wemb  = (const float*)d_in[3];
    const float* cnnA  = (const float*)d_in[4];
    const float* rnnA  = (const float*)d_in[5];
    const float* queue   = (const float*)d_in[6];
    const float* queueIm = (const float*)d_in[7];
    const int*   labels  = (const int*)d_in[9];
    float* W   = (float*)d_ws;
    float* out = (float*)d_out;

    prep_kernel<<<2048, 256, 0, stream>>>(cnn, rnn, img, wemb, cnnA, rnnA, W);
    moco_smat_kernel<<<192, 256, 0, stream>>>(queue, queueIm, W);
    attn_kernel<<<2048, 256, 0, stream>>>(W);
    final_kernel<<<1, 256, 0, stream>>>(labels, W, out);
}